// Round 11
// baseline (159.783 us; speedup 1.0000x reference)
//
#include <hip/hip_runtime.h>

// CREStereo grouped correlation, round 11.
// R10 post-mortem: main kernel VGPR=24 -> the per-k conditional store acted
// as an exec-mask scheduling barrier; only ~4 loads in flight (MLP-starved,
// 9 serialized L2 round-trips per wave). R11:
//  - k-loop batched 3x3 with explicit t[3][4] arrays: 12 tap loads in flight
//    per batch -> 3 memory waits per wave instead of 9.
//  - stores hoisted: rr[9] accumulated (xor-reduce broadcasts to all lanes),
//    ONE masked store block at the end -> exec mask changes once.
//  - transpose + tap-precompute fused into a single dispatch (precompute
//    blocks ride inside the HBM-bound transpose instead of serializing).
// Target VGPR ~100 (between R10's 24-MLP-starved and R6's 172-cliff).

namespace {
constexpr int kB = 2;
constexpr int kC = 256;
constexpr int kH = 96;
constexpr int kW = 192;
constexpr int kG = 4;
constexpr int kGC = kC / kG;              // 64
constexpr int kK = 9;
constexpr int kHW = kH * kW;              // 18432
constexpr size_t kPlane = (size_t)kC * kHW;
constexpr int kTransBlocks = (kHW / 64) * (kC / 64) * kB * 2;   // 4608
constexpr int kPreBlocks   = (kB * kHW) / 256;                  // 144
}

typedef _Float16 half8_t __attribute__((ext_vector_type(8)));
typedef _Float16 half4_t __attribute__((ext_vector_type(4)));
typedef _Float16 half2_t __attribute__((ext_vector_type(2)));

struct TapMeta {        // 32 B: one (b,px,k) candidate
  int4   off;           // element offsets of 4 taps into right_t plane
  float4 wgt;           // bilinear weights (validity folded in)
};

__device__ __forceinline__ float dot8(half8_t a, half8_t b, float acc) {
#if __has_builtin(__builtin_amdgcn_fdot2)
  #pragma unroll
  for (int i = 0; i < 4; ++i) {
    half2_t a2 = {a[2 * i], a[2 * i + 1]};
    half2_t b2 = {b[2 * i], b[2 * i + 1]};
    acc = __builtin_amdgcn_fdot2(a2, b2, acc, false);
  }
#else
  #pragma unroll
  for (int i = 0; i < 8; ++i) acc += (float)a[i] * (float)b[i];
#endif
  return acc;
}

// ---- fused pre-pass: transpose both tensors to fp16 channels-last AND
//      precompute tap meta. 1D grid: [0,4608) transpose, [4608,4752) meta ----
__global__ __launch_bounds__(256) void prepass_kernel(
    const float* __restrict__ left, const float* __restrict__ right,
    const float* __restrict__ flow, const float* __restrict__ extra,
    _Float16* __restrict__ left_t, _Float16* __restrict__ right_t,
    TapMeta* __restrict__ meta)
{
  __shared__ float tile[64][65];
  int id = blockIdx.x;
  if (id < kTransBlocks) {
    int pt = id % (kHW / 64);         // pixel tile 0..287
    int ct = (id / (kHW / 64)) % 4;   // channel tile 0..3
    int z  = id / ((kHW / 64) * 4);   // b*2 + tensor
    int b  = z >> 1;
    const float* in = (z & 1) ? right : left;
    _Float16*   dst = (z & 1) ? right_t : left_t;
    int p0 = pt * 64, c0 = ct * 64;
    const float* inb = in + (size_t)b * kPlane;
    _Float16*   outb = dst + (size_t)b * kPlane;
    int t = threadIdx.x;
    int cl = t >> 2;
    int q  = t & 3;
    #pragma unroll
    for (int i = 0; i < 4; ++i) {
      int j = q + 4 * i;
      float4 v = *(const float4*)(inb + (size_t)(c0 + cl) * kHW + p0 + 4 * j);
      tile[cl][4 * j + 0] = v.x;
      tile[cl][4 * j + 1] = v.y;
      tile[cl][4 * j + 2] = v.z;
      tile[cl][4 * j + 3] = v.w;
    }
    __syncthreads();
    int pl = t >> 2;
    #pragma unroll
    for (int i = 0; i < 4; ++i) {
      int c4 = (t & 3) + 4 * i;
      half4_t hv;
      hv[0] = (_Float16)tile[4 * c4 + 0][pl];
      hv[1] = (_Float16)tile[4 * c4 + 1][pl];
      hv[2] = (_Float16)tile[4 * c4 + 2][pl];
      hv[3] = (_Float16)tile[4 * c4 + 3][pl];
      *(half4_t*)(outb + (size_t)(p0 + pl) * kC + c0 + 4 * c4) = hv;
    }
  } else {
    int t = (id - kTransBlocks) * 256 + threadIdx.x;   // 0 .. B*HW-1
    int b = t / kHW, pix = t % kHW;
    int w = pix % kW, h = pix / kW;

    const float* flowb = flow + (size_t)b * 2 * kHW + pix;
    float bx = (float)w + flowb[0];
    float by = (float)h + flowb[kHW];
    const float* extb = extra + (size_t)b * 2 * kK * kHW + pix;

    TapMeta* mp = meta + (size_t)t * kK;
    #pragma unroll
    for (int k = 0; k < kK; ++k) {
      float xx = bx + (float)(k - 4) + extb[(size_t)(2 * k) * kHW];
      float yy = by + extb[(size_t)(2 * k + 1) * kHW];
      float xf = floorf(xx), yf = floorf(yy);
      float fx = xx - xf, fy = yy - yf;
      int ix0 = (int)xf, iy0 = (int)yf;
      int ix1 = ix0 + 1, iy1 = iy0 + 1;
      bool vx0 = (ix0 >= 0) && (ix0 < kW);
      bool vx1 = (ix1 >= 0) && (ix1 < kW);
      bool vy0 = (iy0 >= 0) && (iy0 < kH);
      bool vy1 = (iy1 >= 0) && (iy1 < kH);
      int xc0 = min(max(ix0, 0), kW - 1);
      int xc1 = min(max(ix1, 0), kW - 1);
      int yc0 = min(max(iy0, 0), kH - 1);
      int yc1 = min(max(iy1, 0), kH - 1);
      float wx0 = 1.f - fx, wy0 = 1.f - fy;
      TapMeta m;
      m.off.x = (yc0 * kW + xc0) * kC;
      m.off.y = (yc0 * kW + xc1) * kC;
      m.off.z = (yc1 * kW + xc0) * kC;
      m.off.w = (yc1 * kW + xc1) * kC;
      m.wgt.x = wx0 * wy0 * ((vx0 && vy0) ? 1.f : 0.f);
      m.wgt.y = fx  * wy0 * ((vx1 && vy0) ? 1.f : 0.f);
      m.wgt.z = wx0 * fy  * ((vx0 && vy1) ? 1.f : 0.f);
      m.wgt.w = fx  * fy  * ((vx1 && vy1) ? 1.f : 0.f);
      mp[k] = m;
    }
  }
}

// ---- main: wave = 2 px x 32 lanes; lane owns 8 ch; k batched 3x3 ----
__global__ __launch_bounds__(256) void corr_fp16_kernel(
    const _Float16* __restrict__ left_t, const _Float16* __restrict__ right_t,
    const TapMeta* __restrict__ meta, float* __restrict__ out)
{
  int gw   = blockIdx.x * 4 + (threadIdx.x >> 6);  // global wave id
  int lane = threadIdx.x & 63;
  int base = gw * 2;            // first of 2 pixels (global, b-major)
  int b    = base / kHW;
  int pl0  = base % kHW;
  int p    = lane >> 5;         // pixel cluster 0..1
  int cl   = lane & 31;         // channel-lane: owns channels cl*8..cl*8+7
  int pix  = pl0 + p;

  half8_t l8 = *(const half8_t*)(left_t + ((size_t)b * kHW + pix) * kC + cl * 8);

  const _Float16* Rb = right_t + (size_t)b * kPlane + cl * 8;
  const TapMeta* mp = meta + (size_t)(base + p) * kK;

  float rr[kK];

  #pragma unroll
  for (int kb = 0; kb < kK; kb += 3) {
    int4   off[3];
    float4 wv[3];
    #pragma unroll
    for (int j = 0; j < 3; ++j) {
      off[j] = mp[kb + j].off;
      wv[j]  = mp[kb + j].wgt;
    }
    half8_t t[3][4];
    #pragma unroll
    for (int j = 0; j < 3; ++j) {
      t[j][0] = *(const half8_t*)(Rb + off[j].x);
      t[j][1] = *(const half8_t*)(Rb + off[j].y);
      t[j][2] = *(const half8_t*)(Rb + off[j].z);
      t[j][3] = *(const half8_t*)(Rb + off[j].w);
    }
    #pragma unroll
    for (int j = 0; j < 3; ++j) {
      float d00 = dot8(t[j][0], l8, 0.f);
      float d01 = dot8(t[j][1], l8, 0.f);
      float d10 = dot8(t[j][2], l8, 0.f);
      float d11 = dot8(t[j][3], l8, 0.f);
      float r = wv[j].x * d00 + wv[j].y * d01 + wv[j].z * d10 + wv[j].w * d11;
      r += __shfl_xor(r, 1);
      r += __shfl_xor(r, 2);
      r += __shfl_xor(r, 4);
      rr[kb + j] = r;           // all lanes hold the group sum
    }
  }

  // single masked store block: exec mask changes once
  int g = cl >> 3;
  if ((cl & 7) == 0) {
    float* outp = out + ((size_t)b * kG + g) * kK * kHW + pix;
    #pragma unroll
    for (int k = 0; k < kK; ++k)
      outp[(size_t)k * kHW] = rr[k] * (1.f / kGC);
  }
}

// ---- fallback (round-2 kernel) if workspace too small ----
__global__ __launch_bounds__(256) void crestereo_corr_fallback(
    const float* __restrict__ left, const float* __restrict__ right,
    const float* __restrict__ flow, const float* __restrict__ extra,
    float* __restrict__ out)
{
  int t = blockIdx.x * blockDim.x + threadIdx.x;
  int w = t % kW;
  int h = (t / kW) % kH;
  int k = (t / kHW) % kK;
  int g = (t / (kHW * kK)) % kG;
  int b = t / (kHW * kK * kG);

  int pix = h * kW + w;
  const float* flowb = flow + b * 2 * kHW + pix;
  float x = (float)(w + (k - 4)) + flowb[0];
  float y = (float)h + flowb[kHW];
  const float* extb = extra + (size_t)(b * 2 * kK + 2 * k) * kHW + pix;
  x += extb[0];
  y += extb[kHW];

  float xf = floorf(x), yf = floorf(y);
  float fx = x - xf, fy = y - yf;
  int ix0 = (int)xf, iy0 = (int)yf;
  int ix1 = ix0 + 1, iy1 = iy0 + 1;
  bool vx0 = (ix0 >= 0) && (ix0 < kW);
  bool vx1 = (ix1 >= 0) && (ix1 < kW);
  bool vy0 = (iy0 >= 0) && (iy0 < kH);
  bool vy1 = (iy1 >= 0) && (iy1 < kH);
  int xc0 = min(max(ix0, 0), kW - 1);
  int xc1 = min(max(ix1, 0), kW - 1);
  int yc0 = min(max(iy0, 0), kH - 1);
  int yc1 = min(max(iy1, 0), kH - 1);
  float wx0 = 1.f - fx, wy0 = 1.f - fy;
  float w00 = wx0 * wy0 * ((vx0 && vy0) ? 1.f : 0.f);
  float w01 = fx  * wy0 * ((vx1 && vy0) ? 1.f : 0.f);
  float w10 = wx0 * fy  * ((vx0 && vy1) ? 1.f : 0.f);
  float w11 = fx  * fy  * ((vx1 && vy1) ? 1.f : 0.f);
  int idx = yc0 * kW + xc0;
  int dx  = xc1 - xc0;
  int dyw = (yc1 - yc0) * kW;

  const float* Rb = right + (size_t)(b * kC + g * kGC) * kHW + idx;
  const float* Lb = left  + (size_t)(b * kC + g * kGC) * kHW + pix;

  float acc = 0.f;
  #pragma unroll 4
  for (int c = 0; c < kGC; ++c) {
    const float* Rc = Rb + (size_t)c * kHW;
    float l   = Lb[(size_t)c * kHW];
    acc += l * (w00 * Rc[0] + w01 * Rc[dx] + w10 * Rc[dyw] + w11 * Rc[dx + dyw]);
  }
  out[(size_t)((b * kG + g) * kK + k) * kHW + pix] = acc * (1.f / kGC);
}

extern "C" void kernel_launch(void* const* d_in, const int* in_sizes, int n_in,
                              void* d_out, int out_size, void* d_ws, size_t ws_size,
                              hipStream_t stream) {
  const float* left  = (const float*)d_in[0];
  const float* right = (const float*)d_in[1];
  const float* flow  = (const float*)d_in[2];
  const float* extra = (const float*)d_in[3];
  float* out = (float*)d_out;

  size_t t_bytes = 2 * (size_t)kB * kPlane * sizeof(_Float16);   // 37.7 MB
  size_t m_bytes = (size_t)kB * kHW * kK * sizeof(TapMeta);      // 10.6 MB
  if (ws_size >= t_bytes + m_bytes) {
    _Float16* left_t  = (_Float16*)d_ws;
    _Float16* right_t = left_t + (size_t)kB * kPlane;
    TapMeta*  meta    = (TapMeta*)((char*)d_ws + t_bytes);

    prepass_kernel<<<kTransBlocks + kPreBlocks, 256, 0, stream>>>(
        left, right, flow, extra, left_t, right_t, meta);
    int waves = kB * kHW / 2;                // 18432 waves, 2 px each
    corr_fp16_kernel<<<waves / 4, 256, 0, stream>>>(left_t, right_t, meta, out);
  } else {
    int total = kB * kG * kK * kH * kW;
    crestereo_corr_fallback<<<(total + 255) / 256, 256, 0, stream>>>(
        left, right, flow, extra, out);
  }
}

// Round 12
// 151.587 us; speedup vs baseline: 1.0541x; 1.0541x over previous
//
#include <hip/hip_runtime.h>

// CREStereo grouped correlation, round 12.
// R11 post-mortem: fused prepass REGRESSED (42us vs 36 unfused) because the
// 144 precompute blocks were appended AFTER the 4608 transpose blocks ->
// dispatched last, ~1 block/2CUs, pure latency tail (+10us serial).
// R12: precompute blocks moved to the grid FRONT so they run concurrently
// with the HBM-bound transpose blocks (different pipes: VALU vs bulk VMEM).
// Main kernel frozen at R11 (2px x 32lane x 8ch, k batched 3x3, meta loads,
// single masked store block) so the prepass delta is the only variable.

namespace {
constexpr int kB = 2;
constexpr int kC = 256;
constexpr int kH = 96;
constexpr int kW = 192;
constexpr int kG = 4;
constexpr int kGC = kC / kG;              // 64
constexpr int kK = 9;
constexpr int kHW = kH * kW;              // 18432
constexpr size_t kPlane = (size_t)kC * kHW;
constexpr int kTransBlocks = (kHW / 64) * (kC / 64) * kB * 2;   // 4608
constexpr int kPreBlocks   = (kB * kHW) / 256;                  // 144
}

typedef _Float16 half8_t __attribute__((ext_vector_type(8)));
typedef _Float16 half4_t __attribute__((ext_vector_type(4)));
typedef _Float16 half2_t __attribute__((ext_vector_type(2)));

struct TapMeta {        // 32 B: one (b,px,k) candidate
  int4   off;           // element offsets of 4 taps into right_t plane
  float4 wgt;           // bilinear weights (validity folded in)
};

__device__ __forceinline__ float dot8(half8_t a, half8_t b, float acc) {
#if __has_builtin(__builtin_amdgcn_fdot2)
  #pragma unroll
  for (int i = 0; i < 4; ++i) {
    half2_t a2 = {a[2 * i], a[2 * i + 1]};
    half2_t b2 = {b[2 * i], b[2 * i + 1]};
    acc = __builtin_amdgcn_fdot2(a2, b2, acc, false);
  }
#else
  #pragma unroll
  for (int i = 0; i < 8; ++i) acc += (float)a[i] * (float)b[i];
#endif
  return acc;
}

// ---- fused pre-pass: grid [0,144) = tap meta, [144, 4752) = transpose ----
__global__ __launch_bounds__(256) void prepass_kernel(
    const float* __restrict__ left, const float* __restrict__ right,
    const float* __restrict__ flow, const float* __restrict__ extra,
    _Float16* __restrict__ left_t, _Float16* __restrict__ right_t,
    TapMeta* __restrict__ meta)
{
  __shared__ float tile[64][65];
  int id = blockIdx.x;
  if (id >= kPreBlocks) {
    int tb = id - kPreBlocks;
    int pt = tb % (kHW / 64);         // pixel tile 0..287
    int ct = (tb / (kHW / 64)) % 4;   // channel tile 0..3
    int z  = tb / ((kHW / 64) * 4);   // b*2 + tensor
    int b  = z >> 1;
    const float* in = (z & 1) ? right : left;
    _Float16*   dst = (z & 1) ? right_t : left_t;
    int p0 = pt * 64, c0 = ct * 64;
    const float* inb = in + (size_t)b * kPlane;
    _Float16*   outb = dst + (size_t)b * kPlane;
    int t = threadIdx.x;
    int cl = t >> 2;
    int q  = t & 3;
    #pragma unroll
    for (int i = 0; i < 4; ++i) {
      int j = q + 4 * i;
      float4 v = *(const float4*)(inb + (size_t)(c0 + cl) * kHW + p0 + 4 * j);
      tile[cl][4 * j + 0] = v.x;
      tile[cl][4 * j + 1] = v.y;
      tile[cl][4 * j + 2] = v.z;
      tile[cl][4 * j + 3] = v.w;
    }
    __syncthreads();
    int pl = t >> 2;
    #pragma unroll
    for (int i = 0; i < 4; ++i) {
      int c4 = (t & 3) + 4 * i;
      half4_t hv;
      hv[0] = (_Float16)tile[4 * c4 + 0][pl];
      hv[1] = (_Float16)tile[4 * c4 + 1][pl];
      hv[2] = (_Float16)tile[4 * c4 + 2][pl];
      hv[3] = (_Float16)tile[4 * c4 + 3][pl];
      *(half4_t*)(outb + (size_t)(p0 + pl) * kC + c0 + 4 * c4) = hv;
    }
  } else {
    int t = id * 256 + threadIdx.x;   // 0 .. B*HW-1
    int b = t / kHW, pix = t % kHW;
    int w = pix % kW, h = pix / kW;

    const float* flowb = flow + (size_t)b * 2 * kHW + pix;
    float bx = (float)w + flowb[0];
    float by = (float)h + flowb[kHW];
    const float* extb = extra + (size_t)b * 2 * kK * kHW + pix;

    TapMeta* mp = meta + (size_t)t * kK;
    #pragma unroll
    for (int k = 0; k < kK; ++k) {
      float xx = bx + (float)(k - 4) + extb[(size_t)(2 * k) * kHW];
      float yy = by + extb[(size_t)(2 * k + 1) * kHW];
      float xf = floorf(xx), yf = floorf(yy);
      float fx = xx - xf, fy = yy - yf;
      int ix0 = (int)xf, iy0 = (int)yf;
      int ix1 = ix0 + 1, iy1 = iy0 + 1;
      bool vx0 = (ix0 >= 0) && (ix0 < kW);
      bool vx1 = (ix1 >= 0) && (ix1 < kW);
      bool vy0 = (iy0 >= 0) && (iy0 < kH);
      bool vy1 = (iy1 >= 0) && (iy1 < kH);
      int xc0 = min(max(ix0, 0), kW - 1);
      int xc1 = min(max(ix1, 0), kW - 1);
      int yc0 = min(max(iy0, 0), kH - 1);
      int yc1 = min(max(iy1, 0), kH - 1);
      float wx0 = 1.f - fx, wy0 = 1.f - fy;
      TapMeta m;
      m.off.x = (yc0 * kW + xc0) * kC;
      m.off.y = (yc0 * kW + xc1) * kC;
      m.off.z = (yc1 * kW + xc0) * kC;
      m.off.w = (yc1 * kW + xc1) * kC;
      m.wgt.x = wx0 * wy0 * ((vx0 && vy0) ? 1.f : 0.f);
      m.wgt.y = fx  * wy0 * ((vx1 && vy0) ? 1.f : 0.f);
      m.wgt.z = wx0 * fy  * ((vx0 && vy1) ? 1.f : 0.f);
      m.wgt.w = fx  * fy  * ((vx1 && vy1) ? 1.f : 0.f);
      mp[k] = m;
    }
  }
}

// ---- main: wave = 2 px x 32 lanes; lane owns 8 ch; k batched 3x3 ----
__global__ __launch_bounds__(256) void corr_fp16_kernel(
    const _Float16* __restrict__ left_t, const _Float16* __restrict__ right_t,
    const TapMeta* __restrict__ meta, float* __restrict__ out)
{
  int gw   = blockIdx.x * 4 + (threadIdx.x >> 6);  // global wave id
  int lane = threadIdx.x & 63;
  int base = gw * 2;            // first of 2 pixels (global, b-major)
  int b    = base / kHW;
  int pl0  = base % kHW;
  int p    = lane >> 5;         // pixel cluster 0..1
  int cl   = lane & 31;         // channel-lane: owns channels cl*8..cl*8+7
  int pix  = pl0 + p;

  half8_t l8 = *(const half8_t*)(left_t + ((size_t)b * kHW + pix) * kC + cl * 8);

  const _Float16* Rb = right_t + (size_t)b * kPlane + cl * 8;
  const TapMeta* mp = meta + (size_t)(base + p) * kK;

  float rr[kK];

  #pragma unroll
  for (int kb = 0; kb < kK; kb += 3) {
    int4   off[3];
    float4 wv[3];
    #pragma unroll
    for (int j = 0; j < 3; ++j) {
      off[j] = mp[kb + j].off;
      wv[j]  = mp[kb + j].wgt;
    }
    half8_t t[3][4];
    #pragma unroll
    for (int j = 0; j < 3; ++j) {
      t[j][0] = *(const half8_t*)(Rb + off[j].x);
      t[j][1] = *(const half8_t*)(Rb + off[j].y);
      t[j][2] = *(const half8_t*)(Rb + off[j].z);
      t[j][3] = *(const half8_t*)(Rb + off[j].w);
    }
    #pragma unroll
    for (int j = 0; j < 3; ++j) {
      float d00 = dot8(t[j][0], l8, 0.f);
      float d01 = dot8(t[j][1], l8, 0.f);
      float d10 = dot8(t[j][2], l8, 0.f);
      float d11 = dot8(t[j][3], l8, 0.f);
      float r = wv[j].x * d00 + wv[j].y * d01 + wv[j].z * d10 + wv[j].w * d11;
      r += __shfl_xor(r, 1);
      r += __shfl_xor(r, 2);
      r += __shfl_xor(r, 4);
      rr[kb + j] = r;           // all lanes hold the group sum
    }
  }

  // single masked store block: exec mask changes once
  int g = cl >> 3;
  if ((cl & 7) == 0) {
    float* outp = out + ((size_t)b * kG + g) * kK * kHW + pix;
    #pragma unroll
    for (int k = 0; k < kK; ++k)
      outp[(size_t)k * kHW] = rr[k] * (1.f / kGC);
  }
}

// ---- fallback (round-2 kernel) if workspace too small ----
__global__ __launch_bounds__(256) void crestereo_corr_fallback(
    const float* __restrict__ left, const float* __restrict__ right,
    const float* __restrict__ flow, const float* __restrict__ extra,
    float* __restrict__ out)
{
  int t = blockIdx.x * blockDim.x + threadIdx.x;
  int w = t % kW;
  int h = (t / kW) % kH;
  int k = (t / kHW) % kK;
  int g = (t / (kHW * kK)) % kG;
  int b = t / (kHW * kK * kG);

  int pix = h * kW + w;
  const float* flowb = flow + b * 2 * kHW + pix;
  float x = (float)(w + (k - 4)) + flowb[0];
  float y = (float)h + flowb[kHW];
  const float* extb = extra + (size_t)(b * 2 * kK + 2 * k) * kHW + pix;
  x += extb[0];
  y += extb[kHW];

  float xf = floorf(x), yf = floorf(y);
  float fx = x - xf, fy = y - yf;
  int ix0 = (int)xf, iy0 = (int)yf;
  int ix1 = ix0 + 1, iy1 = iy0 + 1;
  bool vx0 = (ix0 >= 0) && (ix0 < kW);
  bool vx1 = (ix1 >= 0) && (ix1 < kW);
  bool vy0 = (iy0 >= 0) && (iy0 < kH);
  bool vy1 = (iy1 >= 0) && (iy1 < kH);
  int xc0 = min(max(ix0, 0), kW - 1);
  int xc1 = min(max(ix1, 0), kW - 1);
  int yc0 = min(max(iy0, 0), kH - 1);
  int yc1 = min(max(iy1, 0), kH - 1);
  float wx0 = 1.f - fx, wy0 = 1.f - fy;
  float w00 = wx0 * wy0 * ((vx0 && vy0) ? 1.f : 0.f);
  float w01 = fx  * wy0 * ((vx1 && vy0) ? 1.f : 0.f);
  float w10 = wx0 * fy  * ((vx0 && vy1) ? 1.f : 0.f);
  float w11 = fx  * fy  * ((vx1 && vy1) ? 1.f : 0.f);
  int idx = yc0 * kW + xc0;
  int dx  = xc1 - xc0;
  int dyw = (yc1 - yc0) * kW;

  const float* Rb = right + (size_t)(b * kC + g * kGC) * kHW + idx;
  const float* Lb = left  + (size_t)(b * kC + g * kGC) * kHW + pix;

  float acc = 0.f;
  #pragma unroll 4
  for (int c = 0; c < kGC; ++c) {
    const float* Rc = Rb + (size_t)c * kHW;
    float l   = Lb[(size_t)c * kHW];
    acc += l * (w00 * Rc[0] + w01 * Rc[dx] + w10 * Rc[dyw] + w11 * Rc[dx + dyw]);
  }
  out[(size_t)((b * kG + g) * kK + k) * kHW + pix] = acc * (1.f / kGC);
}

extern "C" void kernel_launch(void* const* d_in, const int* in_sizes, int n_in,
                              void* d_out, int out_size, void* d_ws, size_t ws_size,
                              hipStream_t stream) {
  const float* left  = (const float*)d_in[0];
  const float* right = (const float*)d_in[1];
  const float* flow  = (const float*)d_in[2];
  const float* extra = (const float*)d_in[3];
  float* out = (float*)d_out;

  size_t t_bytes = 2 * (size_t)kB * kPlane * sizeof(_Float16);   // 37.7 MB
  size_t m_bytes = (size_t)kB * kHW * kK * sizeof(TapMeta);      // 10.6 MB
  if (ws_size >= t_bytes + m_bytes) {
    _Float16* left_t  = (_Float16*)d_ws;
    _Float16* right_t = left_t + (size_t)kB * kPlane;
    TapMeta*  meta    = (TapMeta*)((char*)d_ws + t_bytes);

    prepass_kernel<<<kPreBlocks + kTransBlocks, 256, 0, stream>>>(
        left, right, flow, extra, left_t, right_t, meta);
    int waves = kB * kHW / 2;                // 18432 waves, 2 px each
    corr_fp16_kernel<<<waves / 4, 256, 0, stream>>>(left_t, right_t, meta, out);
  } else {
    int total = kB * kG * kK * kH * kW;
    crestereo_corr_fallback<<<(total + 255) / 256, 256, 0, stream>>>(
        left, right, flow, extra, out);
  }
}